// Round 2
// baseline (91.290 us; speedup 1.0000x reference)
//
#include <hip/hip_runtime.h>
#include <hip/hip_bf16.h>
#include <math.h>

#define Bb 64
#define Ss 512
#define Hh 768
#define Ll 9
#define CCH 32      // number of chunks
#define TCH 16      // steps per chunk (S / CCH)

// ---------------- K1: emissions = (hs @ W + b) * cw ----------------
// wave-per-row: lane i owns k = {j*256 + i*4 + e}, W fragment in registers.
__global__ __launch_bounds__(256) void k_emis(
    const float* __restrict__ hs, const float* __restrict__ W,
    const float* __restrict__ bvec, const float* __restrict__ cw,
    float* __restrict__ emis, int nrows)
{
    const int lane  = threadIdx.x & 63;
    const int wave  = blockIdx.x * (blockDim.x >> 6) + (threadIdx.x >> 6);
    const int nwav  = gridDim.x * (blockDim.x >> 6);

    // preload W fragment: 12 k-values x 9 labels
    float w[12][Ll];
#pragma unroll
    for (int j = 0; j < 3; ++j)
#pragma unroll
        for (int e = 0; e < 4; ++e) {
            const int k = j * 256 + lane * 4 + e;
#pragma unroll
            for (int l = 0; l < Ll; ++l) w[j * 4 + e][l] = W[k * Ll + l];
        }
    float bias[Ll], cwv[Ll];
#pragma unroll
    for (int l = 0; l < Ll; ++l) { bias[l] = bvec[l]; cwv[l] = cw[l]; }

    for (int row = wave; row < nrows; row += nwav) {
        const float4* rp = (const float4*)(hs + (size_t)row * Hh);
        float4 x[3];
        x[0] = rp[lane]; x[1] = rp[64 + lane]; x[2] = rp[128 + lane];
        float acc[Ll];
#pragma unroll
        for (int l = 0; l < Ll; ++l) acc[l] = 0.f;
#pragma unroll
        for (int j = 0; j < 3; ++j) {
            const float* xe = (const float*)&x[j];
#pragma unroll
            for (int e = 0; e < 4; ++e) {
                const float xv = xe[e];
#pragma unroll
                for (int l = 0; l < Ll; ++l)
                    acc[l] = fmaf(xv, w[j * 4 + e][l], acc[l]);
            }
        }
        // 64-lane butterfly reduce (all lanes end with full sums)
#pragma unroll
        for (int off = 32; off; off >>= 1)
#pragma unroll
            for (int l = 0; l < Ll; ++l)
                acc[l] += __shfl_xor(acc[l], off);
        if (lane == 0) {
            float* o = emis + (size_t)row * Ll;
#pragma unroll
            for (int l = 0; l < Ll; ++l)
                o[l] = (acc[l] + bias[l]) * cwv[l];
        }
    }
}

// ---------------- K2: per-chunk transfer-matrix rows ----------------
// thread = (b, c, i): row i of chunk c's 9x9 log-matrix, stored normalized:
// rowmax[b][c][i], erow[b][c][i][l] = exp(row - rowmax)
__global__ __launch_bounds__(256) void k_chunks(
    const float* __restrict__ emis, const int* __restrict__ labels,
    const int* __restrict__ attn, const float* __restrict__ trans,
    float* __restrict__ erow, float* __restrict__ rowmax)
{
    const int tid = blockIdx.x * blockDim.x + threadIdx.x;
    if (tid >= Bb * CCH * Ll) return;
    const int i = tid % Ll;
    const int c = (tid / Ll) % CCH;
    const int b = tid / (Ll * CCH);

    float et[Ll][Ll];
#pragma unroll
    for (int l = 0; l < Ll; ++l)
#pragma unroll
        for (int k = 0; k < Ll; ++k) et[l][k] = __expf(trans[l * Ll + k]);

    float v[Ll];
#pragma unroll
    for (int l = 0; l < Ll; ++l) v[l] = (l == i) ? 0.f : -1e30f;

    for (int s = 0; s < TCH; ++s) {
        const int t = c * TCH + s;
        if (t < 1) continue;             // scan steps are t = 1..S-1
        const int lab = labels[b * Ss + t];
        const int att = attn[b * Ss + t];
        const bool mk = (lab != -100) && (att == 1);
        if (mk) {
            const float* e = emis + ((size_t)(b * Ss + t)) * Ll;
            float m = v[0];
#pragma unroll
            for (int l = 1; l < Ll; ++l) m = fmaxf(m, v[l]);
            float p[Ll];
#pragma unroll
            for (int l = 0; l < Ll; ++l) p[l] = __expf(v[l] - m);
            float nv[Ll];
#pragma unroll
            for (int k = 0; k < Ll; ++k) {
                float sacc = 0.f;
#pragma unroll
                for (int l = 0; l < Ll; ++l) sacc = fmaf(p[l], et[l][k], sacc);
                nv[k] = m + __logf(sacc) + e[k];
            }
#pragma unroll
            for (int l = 0; l < Ll; ++l) v[l] = nv[l];
        }
    }
    float m = v[0];
#pragma unroll
    for (int l = 1; l < Ll; ++l) m = fmaxf(m, v[l]);
    rowmax[tid] = m;
    float* er = erow + (size_t)tid * Ll;
#pragma unroll
    for (int l = 0; l < Ll; ++l) er[l] = __expf(v[l] - m);
}

// ---------------- K3: per-batch numerator + chunk-compose + llh ----------------
__global__ __launch_bounds__(64) void k_combine(
    const float* __restrict__ emis, const int* __restrict__ labels,
    const int* __restrict__ attn, const float* __restrict__ trans,
    const float* __restrict__ startt, const float* __restrict__ endt,
    const float* __restrict__ erow, const float* __restrict__ rowmax,
    float* __restrict__ llh)
{
    const int b = blockIdx.x;
    const int lane = threadIdx.x;

    // numerator partial terms + mask count
    float psum = 0.f;
    int pcnt = 0;
    for (int t = lane; t < Ss; t += 64) {
        const int lab = labels[b * Ss + t];
        const int att = attn[b * Ss + t];
        const bool mk = ((lab != -100) && (att == 1)) || (t == 0);
        const int tag = (lab == -100) ? 0 : lab;
        if (t >= 1 && mk) {
            const int labp = labels[b * Ss + t - 1];
            const int tagp = (labp == -100) ? 0 : labp;
            psum += trans[tagp * Ll + tag] + emis[((size_t)(b * Ss + t)) * Ll + tag];
        }
        pcnt += mk ? 1 : 0;
    }
#pragma unroll
    for (int off = 32; off; off >>= 1) {
        psum += __shfl_xor(psum, off);
        pcnt += __shfl_xor(pcnt, off);
    }

    if (lane == 0) {
        const int lab0 = labels[b * Ss];
        const int tag0 = (lab0 == -100) ? 0 : lab0;
        const int last = pcnt - 1;
        const int labL = labels[b * Ss + last];
        const int tagL = (labL == -100) ? 0 : labL;
        float num = startt[tag0] + emis[((size_t)(b * Ss)) * Ll + tag0] + psum + endt[tagL];

        // forward: score0 then compose 32 chunk matrices
        float sc[Ll];
#pragma unroll
        for (int l = 0; l < Ll; ++l) sc[l] = startt[l] + emis[(size_t)b * Ss * Ll + l];
        for (int c = 0; c < CCH; ++c) {
            const float* em = erow + ((size_t)(b * CCH + c) * Ll) * Ll;
            const float* rm = rowmax + (size_t)(b * CCH + c) * Ll;
            float u[Ll];
#pragma unroll
            for (int l = 0; l < Ll; ++l) u[l] = sc[l] + rm[l];
            float M = u[0];
#pragma unroll
            for (int l = 1; l < Ll; ++l) M = fmaxf(M, u[l]);
            float p[Ll];
#pragma unroll
            for (int l = 0; l < Ll; ++l) p[l] = __expf(u[l] - M);
            float ns[Ll];
#pragma unroll
            for (int k = 0; k < Ll; ++k) {
                float sacc = 0.f;
#pragma unroll
                for (int l = 0; l < Ll; ++l) sacc = fmaf(p[l], em[l * Ll + k], sacc);
                ns[k] = M + __logf(sacc);
            }
#pragma unroll
            for (int l = 0; l < Ll; ++l) sc[l] = ns[l];
        }
        float M2 = sc[0] + endt[0];
#pragma unroll
        for (int l = 1; l < Ll; ++l) M2 = fmaxf(M2, sc[l] + endt[l]);
        float s2 = 0.f;
#pragma unroll
        for (int l = 0; l < Ll; ++l) s2 += __expf(sc[l] + endt[l] - M2);
        const float logz = M2 + __logf(s2);
        llh[b] = num - logz;
    }
}

// ---------------- K4: final reduce ----------------
__global__ __launch_bounds__(64) void k_final(const float* __restrict__ llh,
                                              float* __restrict__ out)
{
    const int lane = threadIdx.x;
    float v = llh[lane];
#pragma unroll
    for (int off = 32; off; off >>= 1) v += __shfl_xor(v, off);
    if (lane == 0) out[0] = -v * (1.f / Bb);
}

extern "C" void kernel_launch(void* const* d_in, const int* in_sizes, int n_in,
                              void* d_out, int out_size, void* d_ws, size_t ws_size,
                              hipStream_t stream)
{
    const float* hs     = (const float*)d_in[0];
    const float* W      = (const float*)d_in[1];
    const float* bvec   = (const float*)d_in[2];
    const float* cw     = (const float*)d_in[3];
    const float* startt = (const float*)d_in[4];
    const float* endt   = (const float*)d_in[5];
    const float* trans  = (const float*)d_in[6];
    const int*   labels = (const int*)d_in[7];
    const int*   attn   = (const int*)d_in[8];
    float* out = (float*)d_out;

    float* ws      = (float*)d_ws;
    float* emis    = ws;                                   // 64*512*9 = 294912
    float* erow    = emis + (size_t)Bb * Ss * Ll;          // 64*32*81 = 165888
    float* rowmax  = erow + (size_t)Bb * CCH * Ll * Ll;    // 64*32*9  = 18432
    float* llh     = rowmax + (size_t)Bb * CCH * Ll;       // 64

    const int nrows = Bb * Ss;
    hipLaunchKernelGGL(k_emis, dim3(512), dim3(256), 0, stream,
                       hs, W, bvec, cw, emis, nrows);
    hipLaunchKernelGGL(k_chunks, dim3((Bb * CCH * Ll + 255) / 256), dim3(256), 0, stream,
                       emis, labels, attn, trans, erow, rowmax);
    hipLaunchKernelGGL(k_combine, dim3(Bb), dim3(64), 0, stream,
                       emis, labels, attn, trans, startt, endt, erow, rowmax, llh);
    hipLaunchKernelGGL(k_final, dim3(1), dim3(64), 0, stream, llh, out);
}

// Round 3
// 62.734 us; speedup vs baseline: 1.4552x; 1.4552x over previous
//
#include <hip/hip_runtime.h>
#include <hip/hip_bf16.h>
#include <math.h>

#define Bb 64
#define Ss 512
#define Hh 768
#define Ll 9
#define CCH 32      // chunks per batch
#define TCH 16      // steps per chunk

// ---------------- K1: emissions = (hs @ W + b) * cw ----------------
// wave-per-row: lane i owns k = {j*256 + i*4 + e}; W fragment in registers.
__global__ __launch_bounds__(256) void k_emis(
    const float* __restrict__ hs, const float* __restrict__ W,
    const float* __restrict__ bvec, const float* __restrict__ cw,
    float* __restrict__ emis, int nrows)
{
    const int lane  = threadIdx.x & 63;
    const int wave  = blockIdx.x * (blockDim.x >> 6) + (threadIdx.x >> 6);
    const int nwav  = gridDim.x * (blockDim.x >> 6);

    // preload W fragment: 12 k-values x 9 labels (108 VGPR)
    float w[12][Ll];
#pragma unroll
    for (int j = 0; j < 3; ++j)
#pragma unroll
        for (int e = 0; e < 4; ++e) {
            const int k = j * 256 + lane * 4 + e;
#pragma unroll
            for (int l = 0; l < Ll; ++l) w[j * 4 + e][l] = W[k * Ll + l];
        }
    // per-lane epilogue constants (lane < 9 stores element `lane`)
    const int ml = (lane < Ll) ? lane : 0;
    const float myb = bvec[ml];
    const float myc = cw[ml];

    int row = wave;
    if (row >= nrows) return;
    const float4* rp = (const float4*)(hs + (size_t)row * Hh);
    float4 x0 = rp[lane], x1 = rp[64 + lane], x2 = rp[128 + lane];

    for (; row < nrows; ) {
        const int nrow = row + nwav;
        float acc[Ll];
#pragma unroll
        for (int l = 0; l < Ll; ++l) acc[l] = 0.f;
        {
            const float* xe;
            xe = (const float*)&x0;
#pragma unroll
            for (int e = 0; e < 4; ++e)
#pragma unroll
                for (int l = 0; l < Ll; ++l) acc[l] = fmaf(xe[e], w[e][l], acc[l]);
            xe = (const float*)&x1;
#pragma unroll
            for (int e = 0; e < 4; ++e)
#pragma unroll
                for (int l = 0; l < Ll; ++l) acc[l] = fmaf(xe[e], w[4 + e][l], acc[l]);
            xe = (const float*)&x2;
#pragma unroll
            for (int e = 0; e < 4; ++e)
#pragma unroll
                for (int l = 0; l < Ll; ++l) acc[l] = fmaf(xe[e], w[8 + e][l], acc[l]);
        }
        // prefetch next row before the DS-heavy reduce
        if (nrow < nrows) {
            const float4* np = (const float4*)(hs + (size_t)nrow * Hh);
            x0 = np[lane]; x1 = np[64 + lane]; x2 = np[128 + lane];
        }
        // 64-lane butterfly: afterwards EVERY lane holds all 9 full sums
#pragma unroll
        for (int off = 32; off; off >>= 1)
#pragma unroll
            for (int l = 0; l < Ll; ++l)
                acc[l] += __shfl_xor(acc[l], off);
        // lane j (j<9) stores element j: one contiguous 36B store
        float v = acc[0];
#pragma unroll
        for (int l = 1; l < Ll; ++l) v = (lane == l) ? acc[l] : v;
        if (lane < Ll) emis[(size_t)row * Ll + lane] = (v + myb) * myc;
        row = nrow;
    }
}

// ---------------- K2: fused CRF per batch ----------------
// block b: stage labels/emis/exp(trans) in LDS; 288 chunk workers build
// normalized 9x9 chunk transfer rows in LDS; wave5 does the numerator;
// wave0 (9 lanes) composes the 32 chunks; lane0 atomically adds -llh/B.
__global__ __launch_bounds__(384) void k_crf(
    const float* __restrict__ emis, const int* __restrict__ labels,
    const int* __restrict__ attn, const float* __restrict__ trans,
    const float* __restrict__ startt, const float* __restrict__ endt,
    float* __restrict__ out)
{
    const int b   = blockIdx.x;
    const int tid = threadIdx.x;

    __shared__ int   mkt_s[Ss];          // tag | (mk<<4)
    __shared__ float emis_s[Ss * Ll];    // 18 KB
    __shared__ float et_s[Ll * Ll];      // exp(trans)
    __shared__ float erow_s[CCH * Ll * Ll];
    __shared__ float rowmax_s[CCH * Ll];
    __shared__ float num_s;

    // ---- stage ----
    for (int t = tid; t < Ss; t += 384) {
        const int lab = labels[b * Ss + t];
        const int att = attn[b * Ss + t];
        const int tag = (lab == -100) ? 0 : lab;
        const int mk  = ((lab != -100) && (att == 1)) ? 1 : 0;
        mkt_s[t] = tag | (mk << 4);
    }
    {
        const float4* src = (const float4*)(emis + (size_t)b * Ss * Ll);
        float4* dst = (float4*)emis_s;
#pragma unroll
        for (int i = 0; i < 3; ++i) dst[tid + 384 * i] = src[tid + 384 * i];
    }
    if (tid < Ll * Ll) et_s[tid] = __expf(trans[tid]);
    __syncthreads();

    // ---- chunk workers: tid in [0, 288) ----
    if (tid < CCH * Ll) {
        const int i = tid % Ll;
        const int c = tid / Ll;
        float et[Ll][Ll];
#pragma unroll
        for (int l = 0; l < Ll; ++l)
#pragma unroll
            for (int k = 0; k < Ll; ++k) et[l][k] = et_s[l * Ll + k];
        float v[Ll];
#pragma unroll
        for (int l = 0; l < Ll; ++l) v[l] = (l == i) ? 0.f : -1e30f;
        for (int s = 0; s < TCH; ++s) {
            const int t = c * TCH + s;
            if (t < 1) continue;
            const int mv = mkt_s[t];
            if (mv >> 4) {
                const float* e = emis_s + t * Ll;
                float m = v[0];
#pragma unroll
                for (int l = 1; l < Ll; ++l) m = fmaxf(m, v[l]);
                float p[Ll];
#pragma unroll
                for (int l = 0; l < Ll; ++l) p[l] = __expf(v[l] - m);
                float nv[Ll];
#pragma unroll
                for (int k = 0; k < Ll; ++k) {
                    float sacc = 0.f;
#pragma unroll
                    for (int l = 0; l < Ll; ++l) sacc = fmaf(p[l], et[l][k], sacc);
                    nv[k] = m + __logf(sacc) + e[k];
                }
#pragma unroll
                for (int l = 0; l < Ll; ++l) v[l] = nv[l];
            }
        }
        float m = v[0];
#pragma unroll
        for (int l = 1; l < Ll; ++l) m = fmaxf(m, v[l]);
        rowmax_s[c * Ll + i] = m;
#pragma unroll
        for (int l = 0; l < Ll; ++l) erow_s[(c * Ll + i) * Ll + l] = __expf(v[l] - m);
    }

    // ---- numerator: wave 5 (tid 320..383) ----
    if (tid >= 320) {
        const int lane = tid - 320;
        float psum = 0.f;
        int pcnt = 0;
        for (int t = lane; t < Ss; t += 64) {
            const int mv  = mkt_s[t];
            const int tag = mv & 15;
            const bool mk = (mv >> 4) || (t == 0);
            if (t >= 1 && (mv >> 4)) {
                const int tagp = mkt_s[t - 1] & 15;
                psum += trans[tagp * Ll + tag] + emis_s[t * Ll + tag];
            }
            pcnt += mk ? 1 : 0;
        }
#pragma unroll
        for (int off = 32; off; off >>= 1) {
            psum += __shfl_xor(psum, off);
            pcnt += __shfl_xor(pcnt, off);
        }
        if (lane == 0) {
            const int tag0 = mkt_s[0] & 15;
            const int tagL = mkt_s[pcnt - 1] & 15;
            num_s = startt[tag0] + emis_s[tag0] + psum + endt[tagL];
        }
    }
    __syncthreads();

    // ---- compose: wave 0, lanes 0..8 (lane k owns column k) ----
    if (tid < Ll) {
        const int lane = tid;
        float sc[Ll];
#pragma unroll
        for (int l = 0; l < Ll; ++l) sc[l] = startt[l] + emis_s[l];
        for (int c = 0; c < CCH; ++c) {
            float u[Ll];
#pragma unroll
            for (int l = 0; l < Ll; ++l) u[l] = sc[l] + rowmax_s[c * Ll + l];
            float M = u[0];
#pragma unroll
            for (int l = 1; l < Ll; ++l) M = fmaxf(M, u[l]);
            float sacc = 0.f;
#pragma unroll
            for (int l = 0; l < Ll; ++l)
                sacc = fmaf(__expf(u[l] - M), erow_s[(c * Ll + l) * Ll + lane], sacc);
            const float ns = M + __logf(sacc);
#pragma unroll
            for (int l = 0; l < Ll; ++l) sc[l] = __shfl(ns, l);
        }
        float fin = sc[lane] + endt[lane];
        float M2 = fin;
#pragma unroll
        for (int l = 0; l < Ll; ++l) M2 = fmaxf(M2, __shfl(fin, l));
        float s2 = __expf(fin - M2);
        float tot = 0.f;
#pragma unroll
        for (int l = 0; l < Ll; ++l) tot += __shfl(s2, l);
        if (lane == 0) {
            const float logz = M2 + __logf(tot);
            atomicAdd(out, -(num_s - logz) * (1.f / Bb));
        }
    }
}

extern "C" void kernel_launch(void* const* d_in, const int* in_sizes, int n_in,
                              void* d_out, int out_size, void* d_ws, size_t ws_size,
                              hipStream_t stream)
{
    const float* hs     = (const float*)d_in[0];
    const float* W      = (const float*)d_in[1];
    const float* bvec   = (const float*)d_in[2];
    const float* cw     = (const float*)d_in[3];
    const float* startt = (const float*)d_in[4];
    const float* endt   = (const float*)d_in[5];
    const float* trans  = (const float*)d_in[6];
    const int*   labels = (const int*)d_in[7];
    const int*   attn   = (const int*)d_in[8];
    float* out = (float*)d_out;

    float* emis = (float*)d_ws;   // 64*512*9 floats

    hipMemsetAsync(out, 0, sizeof(float), stream);
    const int nrows = Bb * Ss;
    hipLaunchKernelGGL(k_emis, dim3(1024), dim3(256), 0, stream,
                       hs, W, bvec, cw, emis, nrows);
    hipLaunchKernelGGL(k_crf, dim3(Bb), dim3(384), 0, stream,
                       emis, labels, attn, trans, startt, endt, out);
}